// Round 1
// baseline (13160.255 us; speedup 1.0000x reference)
//
#include <hip/hip_runtime.h>

// BRITS fused persistent-RNN kernel for MI355X (gfx950).
// 512 sequences (2 dirs x 256 batch rows), each block = 2 sequences, 8 waves.
// Weights live in per-lane registers (lane = output feature row).
// grid 256 = #CUs -> 1 block/CU, 2 waves/SIMD.

constexpr int NB = 256;   // batch
constexpr int NT = 1024;  // time
constexpr int ND = 64;    // features D (= H)
constexpr int NG = 256;   // 4*H gate width
constexpr int K2 = 128;   // 2*D

__device__ __forceinline__ float sgm(float v){ return 1.0f/(1.0f+__expf(-v)); }
__device__ __forceinline__ float tnh(float v){
  float a = fabsf(v);
  float e = __expf(-2.0f*a);
  float t = (1.0f-e)/(1.0f+e);
  return v < 0.0f ? -t : t;
}

// dot of 64 register-resident weights against 64 LDS activations (float4 LDS reads,
// 4 accumulators for ILP so a single wave/SIMD still dual-issues)
__device__ __forceinline__ float dot64r(const float* __restrict__ wr,
                                        const float* __restrict__ act){
  float a0=0.f,a1=0.f,a2=0.f,a3=0.f;
  #pragma unroll
  for (int k=0;k<64;k+=4){
    const float4 v = *(const float4*)(act+k);
    a0 = fmaf(wr[k+0], v.x, a0);
    a1 = fmaf(wr[k+1], v.y, a1);
    a2 = fmaf(wr[k+2], v.z, a2);
    a3 = fmaf(wr[k+3], v.w, a3);
  }
  return (a0+a1)+(a2+a3);
}

__device__ __forceinline__ float dot32r(const float* __restrict__ wr,
                                        const float* __restrict__ act){
  float a0=0.f,a1=0.f,a2=0.f,a3=0.f;
  #pragma unroll
  for (int k=0;k<32;k+=4){
    const float4 v = *(const float4*)(act+k);
    a0 = fmaf(wr[k+0], v.x, a0);
    a1 = fmaf(wr[k+1], v.y, a1);
    a2 = fmaf(wr[k+2], v.z, a2);
    a3 = fmaf(wr[k+3], v.w, a3);
  }
  return (a0+a1)+(a2+a3);
}

__global__ __launch_bounds__(512, 1) void brits_fused(
    const float* __restrict__ x_g, const float* __restrict__ m_g,
    const float* __restrict__ Wih_g, const float* __restrict__ Whh_g,
    const float* __restrict__ bih_g, const float* __restrict__ bhh_g,
    const float* __restrict__ Wdh_g, const float* __restrict__ bdh_g,
    const float* __restrict__ wdx_g, const float* __restrict__ bdx_g,
    const float* __restrict__ Whr_g, const float* __restrict__ bhr_g,
    const float* __restrict__ Wfr_g, const float* __restrict__ bfr_g,
    const float* __restrict__ Wwc_g, const float* __restrict__ bwc_g,
    float* __restrict__ out0, float* __restrict__ pred)
{
  const int tid = threadIdx.x;
  const int w   = tid >> 6;   // wave 0..7
  const int l   = tid & 63;   // lane
  const int bid = blockIdx.x; // 0..255
  const int dir = bid >> 7;   // 0 = fwd RITS, 1 = bwd RITS
  const int pair = bid & 127;
  const int b0 = pair*2, b1 = pair*2+1;

  const float* Wih_d = Wih_g + (size_t)dir*NG*K2;
  const float* Whh_d = Whh_g + (size_t)dir*NG*ND;
  const float* bih_d = bih_g + dir*NG;
  const float* bhh_d = bhh_g + dir*NG;
  const float* Wdh_d = Wdh_g + dir*ND*ND;
  const float* bdh_d = bdh_g + dir*ND;
  const float* wdx_d = wdx_g + dir*ND;
  const float* bdx_d = bdx_g + dir*ND;
  const float* Whr_d = Whr_g + dir*ND*ND;
  const float* bhr_d = bhr_g + dir*ND;
  const float* Wfr_d = Wfr_g + dir*ND*ND;
  const float* bfr_d = bfr_g + dir*ND;
  const float* Wwc_d = Wwc_g + dir*ND*K2;
  const float* bwc_d = bwc_g + dir*ND;

  // activation staging (all tiny; broadcast LDS reads are conflict-free)
  __shared__ __align__(16) float h_s [2][ND];   // h(t)
  __shared__ __align__(16) float hd_s[2][ND];   // h(t)*gamma_h(t)
  __shared__ __align__(16) float xh_s[2][ND];
  __shared__ __align__(16) float xc_s[2][ND];
  __shared__ __align__(16) float zp_s[2][2][ND]; // z_h partials [half][seq][l]
  __shared__ __align__(16) float al_s[2][ND];   // alpha(t)
  __shared__ __align__(16) float gh_s[2][ND];   // gamma_h(t+1)
  __shared__ __align__(16) float gx_s[2][ND];   // gamma_x(t+1)
  __shared__ __align__(16) float dl_s[2][ND];   // delta(t+1)
  __shared__ __align__(16) float cc_s[2][ND];
  __shared__ __align__(16) float gt_s[2][NG];   // gate preactivations
  __shared__ __align__(16) float xb_s[2][2][ND]; // x double-buffer [parity][seq][l]
  __shared__ __align__(16) float mb_s[2][2][ND]; // m double-buffer

  // per-wave register-resident weights (all indices compile-time after unroll)
  float wa[K2];
  float wb[ND];
  float bias0 = 0.f;
  float wdx_l = 0.f, bdx_l = 0.f, bfr_l = 0.f;

  if (w == 1){                       // Whr row l
    #pragma unroll
    for (int k=0;k<ND;k+=4){
      const float4 v = *(const float4*)(Whr_d + l*ND + k);
      wa[k]=v.x; wa[k+1]=v.y; wa[k+2]=v.z; wa[k+3]=v.w;
    }
    bias0 = bhr_d[l];
  } else if (w == 2){                // Wwc row l (128) + Wfr row l, k<32 (diag zeroed)
    #pragma unroll
    for (int k=0;k<K2;k+=4){
      const float4 v = *(const float4*)(Wwc_d + l*K2 + k);
      wa[k]=v.x; wa[k+1]=v.y; wa[k+2]=v.z; wa[k+3]=v.w;
    }
    #pragma unroll
    for (int k=0;k<32;k+=4){
      const float4 v = *(const float4*)(Wfr_d + l*ND + k);
      wb[k]   = (k==l)   ? 0.f : v.x;
      wb[k+1] = (k+1==l) ? 0.f : v.y;
      wb[k+2] = (k+2==l) ? 0.f : v.z;
      wb[k+3] = (k+3==l) ? 0.f : v.w;
    }
    bias0 = bwc_d[l];
  } else if (w == 3){                // Wdh row l + Wfr row l, k>=32 (diag zeroed)
    #pragma unroll
    for (int k=0;k<ND;k+=4){
      const float4 v = *(const float4*)(Wdh_d + l*ND + k);
      wa[k]=v.x; wa[k+1]=v.y; wa[k+2]=v.z; wa[k+3]=v.w;
    }
    #pragma unroll
    for (int k=0;k<32;k+=4){
      const float4 v = *(const float4*)(Wfr_d + l*ND + 32 + k);
      wb[k]   = (32+k==l)   ? 0.f : v.x;
      wb[k+1] = (32+k+1==l) ? 0.f : v.y;
      wb[k+2] = (32+k+2==l) ? 0.f : v.z;
      wb[k+3] = (32+k+3==l) ? 0.f : v.w;
    }
    bias0 = bdh_d[l];
  } else if (w >= 4){                // Wih row r (128) + Whh row r (64), r=(w-4)*64+l
    const int r = (w-4)*64 + l;
    #pragma unroll
    for (int k=0;k<K2;k+=4){
      const float4 v = *(const float4*)(Wih_d + r*K2 + k);
      wa[k]=v.x; wa[k+1]=v.y; wa[k+2]=v.z; wa[k+3]=v.w;
    }
    #pragma unroll
    for (int k=0;k<ND;k+=4){
      const float4 v = *(const float4*)(Whh_d + r*ND + k);
      wb[k]=v.x; wb[k+1]=v.y; wb[k+2]=v.z; wb[k+3]=v.w;
    }
    bias0 = bih_d[r] + bhh_d[r];
  }
  if (w < 2){
    wdx_l = wdx_d[l]; bdx_l = bdx_d[l]; bfr_l = bfr_d[l];
  }

  float cst = 0.f;   // cell state (valid in w0: seq0 / w1: seq1)
  float dlt = 0.f;   // delta     (valid in w0/w1)

  // ---- prologue: zero state, prefetch t=0, alpha(0) ----
  if (w == 0){
    #pragma unroll
    for (int s=0;s<2;++s){ h_s[s][l]=0.f; hd_s[s][l]=0.f; dl_s[s][l]=0.f; }
    const int t0 = dir ? (NT-1) : 0;
    #pragma unroll
    for (int s=0;s<2;++s){
      const int bbs = s ? b1 : b0;
      xb_s[0][s][l] = x_g[((size_t)bbs*NT + t0)*ND + l];
      mb_s[0][s][l] = m_g[((size_t)bbs*NT + t0)*ND + l];
    }
  }
  if (w < 2){
    gx_s[w][l] = __expf(-fmaxf(0.f, bdx_l));   // gamma_x(0) with delta=0
  }
  __syncthreads();
  if (w == 2){                                  // alpha(0)
    #pragma unroll
    for (int s=0;s<2;++s){
      const float acc = bias0 + dot64r(wa, &gx_s[s][0]) + dot64r(wa+64, &mb_s[0][s][0]);
      al_s[s][l] = sgm(acc);
    }
  }
  __syncthreads();

  for (int t=0; t<NT; ++t){
    const int cur = t & 1;
    const int nxt = cur ^ 1;
    const int tm  = dir ? (NT-1-t) : t;   // original-time index for I/O

    float ghh0 = 0.f, ghh1 = 0.f;
    // ---- P1: x_h/x_c (w1) | Whh*hdec partial (w4..7) | prefetch x,m(t+1) (w0) ----
    if (w == 0){
      if (t+1 < NT){
        const int tn = dir ? (NT-2-t) : (t+1);
        #pragma unroll
        for (int s=0;s<2;++s){
          const int bbs = s ? b1 : b0;
          xb_s[nxt][s][l] = x_g[((size_t)bbs*NT + tn)*ND + l];
          mb_s[nxt][s][l] = m_g[((size_t)bbs*NT + tn)*ND + l];
        }
      }
    } else if (w == 1){
      #pragma unroll
      for (int s=0;s<2;++s){
        const float xh = bias0 + dot64r(wa, &h_s[s][0]);
        xh_s[s][l] = xh;
        const float mm = mb_s[cur][s][l];
        const float xx = xb_s[cur][s][l];
        xc_s[s][l] = mm*xx + (1.f-mm)*xh;
        const int bbs = s ? b1 : b0;
        pred[(size_t)(4+dir)*NB*NT*ND + ((size_t)bbs*NT + tm)*ND + l] = xh;
      }
    } else if (w >= 4){
      ghh0 = bias0 + dot64r(wb, &hd_s[0][0]);
      ghh1 = bias0 + dot64r(wb, &hd_s[1][0]);
    }
    __syncthreads();
    // ---- P2: z_h partials (K-split across w2/w3) ----
    if (w == 2){
      zp_s[0][0][l] = dot32r(wb, &xc_s[0][0]);
      zp_s[0][1][l] = dot32r(wb, &xc_s[1][0]);
    } else if (w == 3){
      zp_s[1][0][l] = dot32r(wb, &xc_s[0][32]);
      zp_s[1][1][l] = dot32r(wb, &xc_s[1][32]);
    }
    __syncthreads();
    // ---- P3: elementwise c_h/c_c + outputs + delta/gamma_x(t+1)  (w0: seq0, w1: seq1) ----
    if (w < 2){
      const int s = w;
      const int bbs = s ? b1 : b0;
      const float mm = mb_s[cur][s][l];
      const float xx = xb_s[cur][s][l];
      const float zh = zp_s[0][s][l] + zp_s[1][s][l] + bfr_l;
      const float a  = al_s[s][l];
      const float xh = xh_s[s][l];
      const float ch = a*zh + (1.f-a)*xh;
      const float cc = mm*xx + (1.f-mm)*ch;
      cc_s[s][l] = cc;
      const size_t ob = ((size_t)bbs*NT + tm)*ND + l;
      pred[(size_t)(0+dir)*NB*NT*ND + ob] = ch;
      pred[(size_t)(2+dir)*NB*NT*ND + ob] = zh;
      atomicAdd(&out0[ob], 0.5f*cc);           // mean over the two directions
      dlt = 1.0f + (1.0f-mm)*dlt;              // delta(t+1)
      dl_s[s][l] = dlt;
      gx_s[s][l] = __expf(-fmaxf(0.f, fmaf(dlt, wdx_l, bdx_l)));  // gamma_x(t+1)
    }
    __syncthreads();
    // ---- P4: gates (w4..7) | alpha(t+1) (w2) | gamma_h(t+1) (w3) ----
    if (w >= 4){
      const float g0 = ghh0 + dot64r(wa, &cc_s[0][0]) + dot64r(wa+64, &mb_s[cur][0][0]);
      const float g1 = ghh1 + dot64r(wa, &cc_s[1][0]) + dot64r(wa+64, &mb_s[cur][1][0]);
      const int r = (w-4)*64 + l;
      gt_s[0][r] = g0;
      gt_s[1][r] = g1;
    } else if (w == 2){
      if (t+1 < NT){
        #pragma unroll
        for (int s=0;s<2;++s){
          const float acc = bias0 + dot64r(wa, &gx_s[s][0]) + dot64r(wa+64, &mb_s[nxt][s][0]);
          al_s[s][l] = sgm(acc);
        }
      }
    } else if (w == 3){
      if (t+1 < NT){
        #pragma unroll
        for (int s=0;s<2;++s){
          gh_s[s][l] = __expf(-fmaxf(0.f, bias0 + dot64r(wa, &dl_s[s][0])));
        }
      }
    }
    __syncthreads();
    // ---- P5: LSTM cell + stage h(t+1), hdec(t+1) ----
    if (w < 2){
      const int s = w;
      const float gi = gt_s[s][l];
      const float gf = gt_s[s][64+l];
      const float gg = gt_s[s][128+l];
      const float go = gt_s[s][192+l];
      cst = sgm(gf)*cst + sgm(gi)*tnh(gg);
      const float hn = sgm(go)*tnh(cst);
      h_s[s][l]  = hn;
      hd_s[s][l] = hn * gh_s[s][l];   // gamma_h(t+1) written in P4
    }
    __syncthreads();
  }
}

extern "C" void kernel_launch(void* const* d_in, const int* in_sizes, int n_in,
                              void* d_out, int out_size, void* d_ws, size_t ws_size,
                              hipStream_t stream) {
  (void)in_sizes; (void)n_in; (void)d_ws; (void)ws_size; (void)out_size;
  const float* x   = (const float*)d_in[0];
  const float* m   = (const float*)d_in[1];
  const float* Wih = (const float*)d_in[2];
  const float* Whh = (const float*)d_in[3];
  const float* bih = (const float*)d_in[4];
  const float* bhh = (const float*)d_in[5];
  const float* Wdh = (const float*)d_in[6];
  const float* bdh = (const float*)d_in[7];
  const float* wdx = (const float*)d_in[8];
  const float* bdx = (const float*)d_in[9];
  const float* Whr = (const float*)d_in[10];
  const float* bhr = (const float*)d_in[11];
  const float* Wfr = (const float*)d_in[12];
  const float* bfr = (const float*)d_in[13];
  const float* Wwc = (const float*)d_in[14];
  const float* bwc = (const float*)d_in[15];

  float* out  = (float*)d_out;                       // [B,T,D,1] mean imputation
  float* pred = out + (size_t)NB*NT*ND;              // [6,B,T,D,1]

  // out0 is accumulated by both directions via atomicAdd -> zero it first
  // (d_out is re-poisoned before every timed launch).
  hipMemsetAsync(out, 0, (size_t)NB*NT*ND*sizeof(float), stream);

  brits_fused<<<dim3(256), dim3(512), 0, stream>>>(
      x, m, Wih, Whh, bih, bhh, Wdh, bdh, wdx, bdx,
      Whr, bhr, Wfr, bfr, Wwc, bwc, out, pred);
}